// Round 2
// baseline (5228.429 us; speedup 1.0000x reference)
//
#include <hip/hip_runtime.h>
#include <hip/hip_fp16.h>

typedef _Float16 half8 __attribute__((ext_vector_type(8)));
typedef _Float16 half4v __attribute__((ext_vector_type(4)));
typedef float f32x4 __attribute__((ext_vector_type(4)));

#define T_INS 200
#define NB 16

// LDS byte offsets
constexpr int H0O = 0;       // 2 x 4096 (parity)
constexpr int H1O = 8192;    // 2 x 4096
constexpr int XTO = 16384;   // 2 x 4096
constexpr int BIO = 24576;   // float[2][512] gate-interleaved biases
constexpr int SMSZ = 24576 + 4096;

// swizzled [batch][k(half)] f16 layout
#define OFF(b, k) (((((b) << 8) | ((k) << 1))) ^ (((b) & 7) << 4))

// counted barrier: publish LDS, do NOT drain vmcnt (keeps global loads/stores in flight)
#define BARRIER() asm volatile("s_waitcnt lgkmcnt(0)\n\ts_barrier" ::: "memory")

__device__ __forceinline__ float sigm(float x) {
  return __builtin_amdgcn_rcpf(1.0f + __builtin_amdgcn_exp2f(-1.44269504f * x));
}
__device__ __forceinline__ float tanh_f(float x) {
  return 1.0f - 2.0f * __builtin_amdgcn_rcpf(1.0f + __builtin_amdgcn_exp2f(2.88539008f * x));
}
__device__ __forceinline__ half8 cvt_frag(const float* __restrict__ src) {
  f32x4 a = *(const f32x4*)src;
  f32x4 b = *(const f32x4*)(src + 4);
  half8 h;
  h[0] = (_Float16)a[0]; h[1] = (_Float16)a[1]; h[2] = (_Float16)a[2]; h[3] = (_Float16)a[3];
  h[4] = (_Float16)b[0]; h[5] = (_Float16)b[1]; h[6] = (_Float16)b[2]; h[7] = (_Float16)b[3];
  return h;
}

// Pack W_ih AND W_hh into f16 MFMA A-fragments in ws (512 frags x 1KB = 512KB).
// Frag G: 0..255 = ih, 256..511 = hh; within: (l*8+w)*16 + mt*4 + kf.
// Row perm: orig_row = gate*128 + (w*16 + (r>>2)*4 + mt), gate = r&3, r = row-in-tile.
__global__ __launch_bounds__(256) void pack_kernel(const float* __restrict__ W_ih,
                                                   const float* __restrict__ W_hh,
                                                   char* __restrict__ ws) {
  int gid = blockIdx.x * 256 + threadIdx.x;  // 32768 threads exactly
  int G = gid >> 6, lane = gid & 63;
  int isH = G >> 8, F = G & 255;
  int l = F >> 7, w = (F >> 4) & 7, mt = (F >> 2) & 3, kf = F & 3;
  int r = lane & 15;
  int row = (r & 3) * 128 + w * 16 + (r >> 2) * 4 + mt;
  int k0 = kf * 32 + (lane >> 4) * 8;
  const float* src = (isH ? W_hh : W_ih) + (size_t)(l * 512 + row) * 128 + k0;
  *(half8*)(ws + (size_t)G * 1024 + lane * 16) = cvt_frag(src);
}

__global__ __launch_bounds__(512, 2) void lstm_kernel(
    const float* __restrict__ x, const int* __restrict__ len_in,
    const int* __restrict__ len_ar, const float* __restrict__ W_ih,
    const float* __restrict__ W_hh, const float* __restrict__ b_ih,
    const float* __restrict__ b_hh, const char* __restrict__ ws,
    float* __restrict__ out, int packed) {
  __shared__ __attribute__((aligned(16))) char sm[SMSZ];
  float* biasS = (float*)(sm + BIO);

  const int tid = threadIdx.x;
  const int w = tid >> 6, lane = tid & 63;
  const int lb = lane & 15, lg = lane >> 4;
  const int k0b = lg * 8;
  const int u0 = w * 16 + lg * 4;  // lane's 4 contiguous units are u0..u0+3
  const int batch = blockIdx.x * NB + lb;
  const int Lin = len_in[batch];
  const int Lar = len_ar[batch];

  // fallback-path row indices (r = lb)
  int rowi[4];
#pragma unroll
  for (int mt = 0; mt < 4; ++mt)
    rowi[mt] = (lb & 3) * 128 + w * 16 + (lb >> 2) * 4 + mt;

  // biases gate-interleaved into LDS: biasS[l*512 + u*4 + q]
#pragma unroll
  for (int l = 0; l < 2; ++l) {
    int u = tid >> 2, q = tid & 3;
    biasS[l * 512 + tid] = b_ih[l * 512 + q * 128 + u] + b_hh[l * 512 + q * 128 + u];
  }
  // zero h0/h1 buffers (both parities)
#pragma unroll
  for (int i = 0; i < 2; ++i)
    *(f32x4*)(sm + tid * 16 + i * 8192) = (f32x4){0.f, 0.f, 0.f, 0.f};
  // load x(t=0) into XT[0]
  {
    int bb = tid >> 5, k4 = (tid & 31) * 4;
    int bg = blockIdx.x * NB + bb;
    f32x4 v = *(const f32x4*)(x + ((size_t)bg * T_INS) * 128 + k4);
    half4v hx;
    hx[0] = (_Float16)v[0]; hx[1] = (_Float16)v[1];
    hx[2] = (_Float16)v[2]; hx[3] = (_Float16)v[3];
    *(half4v*)(sm + XTO + OFF(bb, k4)) = hx;
  }

  float c0[4] = {0, 0, 0, 0}, c1[4] = {0, 0, 0, 0};
  float hp0[4] = {0, 0, 0, 0}, hp1[4] = {0, 0, 0, 0};
  __syncthreads();

  // streamed weight fragment buffers (double use: ih in wA, hh in wB)
  half8 wA[16], wB[16];
  const char* wsl = ws + (size_t)lane * 16;
  const size_t wbase = (size_t)(w * 16) * 1024;

#define ISSUE_L(lsel)                                                        \
  do {                                                                       \
    const char* ibA = wsl + wbase + (size_t)(lsel) * 131072;                 \
    _Pragma("unroll") for (int f = 0; f < 16; ++f)                           \
        wA[f] = *(const half8*)(ibA + f * 1024);                             \
    _Pragma("unroll") for (int f = 0; f < 16; ++f)                           \
        wB[f] = *(const half8*)(ibA + 262144 + f * 1024);                    \
  } while (0)

  if (packed) ISSUE_L(0);

  const int xb = tid >> 5, xk4 = (tid & 31) * 4;
  const int xbg = blockIdx.x * NB + xb;

  for (int t = 0; t < 400; ++t) {
    const int p = t & 1;
    const bool doX = (t < 199);
    f32x4 xpre = (f32x4){0.f, 0.f, 0.f, 0.f};
    if (doX)
      xpre = *(const f32x4*)(x + ((size_t)xbg * T_INS + (t + 1)) * 128 + xk4);

    const bool mk = (t < 200) ? (t < Lin) : ((t - 200) < Lar);

    // ================= layer 0 =================
    {
      const char* sX = (t < 200) ? (sm + XTO + p * 4096) : (sm + H1O + p * 4096);
      const char* sH = sm + H0O + (p ^ 1) * 4096;
      half8 bfX[4], bfH[4];
#pragma unroll
      for (int kf = 0; kf < 4; ++kf)
        bfX[kf] = *(const half8*)(sX + OFF(lb, kf * 32 + k0b));
#pragma unroll
      for (int kf = 0; kf < 4; ++kf)
        bfH[kf] = *(const half8*)(sH + OFF(lb, kf * 32 + k0b));
      f32x4 bb[4];
#pragma unroll
      for (int mt = 0; mt < 4; ++mt)
        bb[mt] = *(const f32x4*)(biasS + (u0 + mt) * 4);

      f32x4 acc[4] = {{0, 0, 0, 0}, {0, 0, 0, 0}, {0, 0, 0, 0}, {0, 0, 0, 0}};
      if (packed) {
#pragma unroll
        for (int mt = 0; mt < 4; ++mt)
#pragma unroll
          for (int kf = 0; kf < 4; ++kf)
            acc[mt] = __builtin_amdgcn_mfma_f32_16x16x32_f16(wA[mt * 4 + kf], bfX[kf],
                                                             acc[mt], 0, 0, 0);
#pragma unroll
        for (int mt = 0; mt < 4; ++mt)
#pragma unroll
          for (int kf = 0; kf < 4; ++kf)
            acc[mt] = __builtin_amdgcn_mfma_f32_16x16x32_f16(wB[mt * 4 + kf], bfH[kf],
                                                             acc[mt], 0, 0, 0);
      } else {
#pragma unroll
        for (int mt = 0; mt < 4; ++mt)
#pragma unroll
          for (int kf = 0; kf < 4; ++kf) {
            half8 a = cvt_frag(W_ih + (size_t)rowi[mt] * 128 + kf * 32 + k0b);
            acc[mt] = __builtin_amdgcn_mfma_f32_16x16x32_f16(a, bfX[kf], acc[mt], 0, 0, 0);
            half8 b = cvt_frag(W_hh + (size_t)rowi[mt] * 128 + kf * 32 + k0b);
            acc[mt] = __builtin_amdgcn_mfma_f32_16x16x32_f16(b, bfH[kf], acc[mt], 0, 0, 0);
          }
      }
      // ACT0
      _Float16 h4[4];
#pragma unroll
      for (int mt = 0; mt < 4; ++mt) {
        float si = sigm(acc[mt][0] + bb[mt][0]);
        float sf = sigm(acc[mt][1] + bb[mt][1]);
        float tg = tanh_f(acc[mt][2] + bb[mt][2]);
        float so = sigm(acc[mt][3] + bb[mt][3]);
        float cn = sf * c0[mt] + si * tg;
        float hn = so * tanh_f(cn);
        c0[mt] = mk ? cn : c0[mt];
        hp0[mt] = mk ? hn : hp0[mt];
        h4[mt] = (_Float16)hp0[mt];
      }
      *(half4v*)(sm + H0O + p * 4096 + OFF(lb, u0)) = *(half4v*)h4;
      if (packed) ISSUE_L(1);  // prefetch layer-1 frags across the barrier
    }
    BARRIER();  // h0[p] published; vmcnt NOT drained

    // stage x(t+1) into XT[p^1]
    if (doX) {
      half4v hx;
      hx[0] = (_Float16)xpre[0]; hx[1] = (_Float16)xpre[1];
      hx[2] = (_Float16)xpre[2]; hx[3] = (_Float16)xpre[3];
      *(half4v*)(sm + XTO + (p ^ 1) * 4096 + OFF(xb, xk4)) = hx;
    }

    // ================= layer 1 =================
    {
      const char* sX = sm + H0O + p * 4096;   // fresh h0(t)
      const char* sH = sm + H1O + p * 4096;   // h1(t-1)
      half8 bfX[4], bfH[4];
#pragma unroll
      for (int kf = 0; kf < 4; ++kf)
        bfX[kf] = *(const half8*)(sX + OFF(lb, kf * 32 + k0b));
#pragma unroll
      for (int kf = 0; kf < 4; ++kf)
        bfH[kf] = *(const half8*)(sH + OFF(lb, kf * 32 + k0b));
      f32x4 bb[4];
#pragma unroll
      for (int mt = 0; mt < 4; ++mt)
        bb[mt] = *(const f32x4*)(biasS + 512 + (u0 + mt) * 4);

      f32x4 acc[4] = {{0, 0, 0, 0}, {0, 0, 0, 0}, {0, 0, 0, 0}, {0, 0, 0, 0}};
      if (packed) {
#pragma unroll
        for (int mt = 0; mt < 4; ++mt)
#pragma unroll
          for (int kf = 0; kf < 4; ++kf)
            acc[mt] = __builtin_amdgcn_mfma_f32_16x16x32_f16(wA[mt * 4 + kf], bfX[kf],
                                                             acc[mt], 0, 0, 0);
#pragma unroll
        for (int mt = 0; mt < 4; ++mt)
#pragma unroll
          for (int kf = 0; kf < 4; ++kf)
            acc[mt] = __builtin_amdgcn_mfma_f32_16x16x32_f16(wB[mt * 4 + kf], bfH[kf],
                                                             acc[mt], 0, 0, 0);
      } else {
#pragma unroll
        for (int mt = 0; mt < 4; ++mt)
#pragma unroll
          for (int kf = 0; kf < 4; ++kf) {
            half8 a = cvt_frag(W_ih + (size_t)(512 + rowi[mt]) * 128 + kf * 32 + k0b);
            acc[mt] = __builtin_amdgcn_mfma_f32_16x16x32_f16(a, bfX[kf], acc[mt], 0, 0, 0);
            half8 b = cvt_frag(W_hh + (size_t)(512 + rowi[mt]) * 128 + kf * 32 + k0b);
            acc[mt] = __builtin_amdgcn_mfma_f32_16x16x32_f16(b, bfH[kf], acc[mt], 0, 0, 0);
          }
      }
      // ACT1 + output
      _Float16 h4[4];
      f32x4 vo;
#pragma unroll
      for (int mt = 0; mt < 4; ++mt) {
        float si = sigm(acc[mt][0] + bb[mt][0]);
        float sf = sigm(acc[mt][1] + bb[mt][1]);
        float tg = tanh_f(acc[mt][2] + bb[mt][2]);
        float so = sigm(acc[mt][3] + bb[mt][3]);
        float cn = sf * c1[mt] + si * tg;
        float hn = so * tanh_f(cn);
        c1[mt] = mk ? cn : c1[mt];
        hp1[mt] = mk ? hn : hp1[mt];
        h4[mt] = (_Float16)hp1[mt];
        vo[mt] = mk ? hn : 0.0f;
      }
      *(half4v*)(sm + H1O + (p ^ 1) * 4096 + OFF(lb, u0)) = *(half4v*)h4;
      size_t oix = (t < 200)
                       ? ((size_t)batch * 25600 + (size_t)t * 128 + u0)
                       : (13107200ull + (size_t)batch * 25600 + (size_t)(t - 200) * 128 + u0);
      *(f32x4*)(out + oix) = vo;
      if (packed) ISSUE_L(0);  // prefetch next step's layer-0 frags
    }
    BARRIER();  // h1[p^1], XT[p^1] published
  }
}

extern "C" void kernel_launch(void* const* d_in, const int* in_sizes, int n_in,
                              void* d_out, int out_size, void* d_ws, size_t ws_size,
                              hipStream_t stream) {
  (void)in_sizes; (void)n_in; (void)out_size;
  const float* x = (const float*)d_in[0];
  const int* len_in = (const int*)d_in[1];
  const int* len_ar = (const int*)d_in[2];
  // d_in[3] = mask_aureg (bool) unused; recomputed from lengths (monotone mask)
  const float* W_ih = (const float*)d_in[4];
  const float* W_hh = (const float*)d_in[5];
  const float* b_ih = (const float*)d_in[6];
  const float* b_hh = (const float*)d_in[7];
  float* out = (float*)d_out;
  char* ws = (char*)d_ws;

  int packed = (ws_size >= (size_t)524288) ? 1 : 0;
  if (packed) pack_kernel<<<dim3(128), dim3(256), 0, stream>>>(W_ih, W_hh, ws);
  lstm_kernel<<<dim3(32), dim3(512), 0, stream>>>(x, len_in, len_ar, W_ih, W_hh,
                                                  b_ih, b_hh, ws, out, packed);
}

// Round 3
// 5222.579 us; speedup vs baseline: 1.0011x; 1.0011x over previous
//
#include <hip/hip_runtime.h>
#include <hip/hip_fp16.h>

typedef _Float16 half8 __attribute__((ext_vector_type(8)));
typedef _Float16 half4v __attribute__((ext_vector_type(4)));
typedef float f32x4 __attribute__((ext_vector_type(4)));

#define T_INS 200
#define NB 16

// LDS byte offsets
constexpr int H0O = 0;       // 2 x 4096 (parity)
constexpr int H1O = 8192;    // 2 x 4096
constexpr int XTO = 16384;   // 2 x 4096
constexpr int BIO = 24576;   // float[2][512] gate-interleaved biases
constexpr int SMSZ = 24576 + 4096;

// swizzled [batch][k(half)] f16 layout
#define OFF(b, k) (((((b) << 8) | ((k) << 1))) ^ (((b) & 7) << 4))

// counted barrier: publish LDS, do NOT drain vmcnt (keeps global loads/stores in flight)
#define BARRIER() asm volatile("s_waitcnt lgkmcnt(0)\n\ts_barrier" ::: "memory")

__device__ __forceinline__ float sigm(float x) {
  return __builtin_amdgcn_rcpf(1.0f + __builtin_amdgcn_exp2f(-1.44269504f * x));
}
__device__ __forceinline__ float tanh_f(float x) {
  return 1.0f - 2.0f * __builtin_amdgcn_rcpf(1.0f + __builtin_amdgcn_exp2f(2.88539008f * x));
}
__device__ __forceinline__ half8 cvt_frag(const float* __restrict__ src) {
  f32x4 a = *(const f32x4*)src;
  f32x4 b = *(const f32x4*)(src + 4);
  half8 h;
  h[0] = (_Float16)a[0]; h[1] = (_Float16)a[1]; h[2] = (_Float16)a[2]; h[3] = (_Float16)a[3];
  h[4] = (_Float16)b[0]; h[5] = (_Float16)b[1]; h[6] = (_Float16)b[2]; h[7] = (_Float16)b[3];
  return h;
}

// Pack W_ih AND W_hh into f16 MFMA A-fragments in ws (512 frags x 1KB = 512KB).
// Frag G: 0..255 = ih, 256..511 = hh; within: (l*8+w)*16 + mt*4 + kf.
// Row perm: orig_row = gate*128 + (w*16 + (r>>2)*4 + mt), gate = r&3, r = row-in-tile.
__global__ __launch_bounds__(256) void pack_kernel(const float* __restrict__ W_ih,
                                                   const float* __restrict__ W_hh,
                                                   char* __restrict__ ws) {
  int gid = blockIdx.x * 256 + threadIdx.x;  // 32768 threads exactly
  int G = gid >> 6, lane = gid & 63;
  int isH = G >> 8, F = G & 255;
  int l = F >> 7, w = (F >> 4) & 7, mt = (F >> 2) & 3, kf = F & 3;
  int r = lane & 15;
  int row = (r & 3) * 128 + w * 16 + (r >> 2) * 4 + mt;
  int k0 = kf * 32 + (lane >> 4) * 8;
  const float* src = (isH ? W_hh : W_ih) + (size_t)(l * 512 + row) * 128 + k0;
  *(half8*)(ws + (size_t)G * 1024 + lane * 16) = cvt_frag(src);
}

__global__ __launch_bounds__(512, 2) void lstm_kernel(
    const float* __restrict__ x, const int* __restrict__ len_in,
    const int* __restrict__ len_ar, const float* __restrict__ W_ih,
    const float* __restrict__ W_hh, const float* __restrict__ b_ih,
    const float* __restrict__ b_hh, const char* __restrict__ ws,
    float* __restrict__ out, int packed) {
  __shared__ __attribute__((aligned(16))) char sm[SMSZ];
  float* biasS = (float*)(sm + BIO);

  const int tid = threadIdx.x;
  const int w = tid >> 6, lane = tid & 63;
  const int lb = lane & 15, lg = lane >> 4;
  const int k0b = lg * 8;
  const int u0 = w * 16 + lg * 4;  // lane's 4 contiguous units are u0..u0+3
  const int batch = blockIdx.x * NB + lb;
  const int Lin = len_in[batch];
  const int Lar = len_ar[batch];

  // fallback-path row indices (r = lb)
  int rowi[4];
#pragma unroll
  for (int mt = 0; mt < 4; ++mt)
    rowi[mt] = (lb & 3) * 128 + w * 16 + (lb >> 2) * 4 + mt;

  // biases gate-interleaved into LDS: biasS[l*512 + u*4 + q]
#pragma unroll
  for (int l = 0; l < 2; ++l) {
    int u = tid >> 2, q = tid & 3;
    biasS[l * 512 + tid] = b_ih[l * 512 + q * 128 + u] + b_hh[l * 512 + q * 128 + u];
  }
  // zero h0/h1 buffers (both parities)
#pragma unroll
  for (int i = 0; i < 2; ++i)
    *(f32x4*)(sm + tid * 16 + i * 8192) = (f32x4){0.f, 0.f, 0.f, 0.f};
  // load x(t=0) into XT[0]
  {
    int bb = tid >> 5, k4 = (tid & 31) * 4;
    int bg = blockIdx.x * NB + bb;
    f32x4 v = *(const f32x4*)(x + ((size_t)bg * T_INS) * 128 + k4);
    half4v hx;
    hx[0] = (_Float16)v[0]; hx[1] = (_Float16)v[1];
    hx[2] = (_Float16)v[2]; hx[3] = (_Float16)v[3];
    *(half4v*)(sm + XTO + OFF(bb, k4)) = hx;
  }

  float c0[4] = {0, 0, 0, 0}, c1[4] = {0, 0, 0, 0};
  float hp0[4] = {0, 0, 0, 0}, hp1[4] = {0, 0, 0, 0};
  __syncthreads();

  // streamed weight fragment buffers (double use: ih in wA, hh in wB)
  half8 wA[16], wB[16];
  const char* wsl = ws + (size_t)lane * 16;
  const size_t wbase = (size_t)(w * 16) * 1024;

#define ISSUE_L(lsel)                                                        \
  do {                                                                       \
    const char* ibA = wsl + wbase + (size_t)(lsel) * 131072;                 \
    _Pragma("unroll") for (int f = 0; f < 16; ++f)                           \
        wA[f] = *(const half8*)(ibA + f * 1024);                             \
    _Pragma("unroll") for (int f = 0; f < 16; ++f)                           \
        wB[f] = *(const half8*)(ibA + 262144 + f * 1024);                    \
  } while (0)

  if (packed) ISSUE_L(0);

  const int xb = tid >> 5, xk4 = (tid & 31) * 4;
  const int xbg = blockIdx.x * NB + xb;

  for (int t = 0; t < 400; ++t) {
    const int p = t & 1;
    const bool doX = (t < 199);
    f32x4 xpre = (f32x4){0.f, 0.f, 0.f, 0.f};
    if (doX)
      xpre = *(const f32x4*)(x + ((size_t)xbg * T_INS + (t + 1)) * 128 + xk4);

    const bool mk = (t < 200) ? (t < Lin) : ((t - 200) < Lar);

    // ================= layer 0 =================
    {
      const char* sX = (t < 200) ? (sm + XTO + p * 4096) : (sm + H1O + p * 4096);
      const char* sH = sm + H0O + (p ^ 1) * 4096;
      half8 bfX[4], bfH[4];
#pragma unroll
      for (int kf = 0; kf < 4; ++kf)
        bfX[kf] = *(const half8*)(sX + OFF(lb, kf * 32 + k0b));
#pragma unroll
      for (int kf = 0; kf < 4; ++kf)
        bfH[kf] = *(const half8*)(sH + OFF(lb, kf * 32 + k0b));
      f32x4 bb[4];
#pragma unroll
      for (int mt = 0; mt < 4; ++mt)
        bb[mt] = *(const f32x4*)(biasS + (u0 + mt) * 4);

      f32x4 acc[4] = {{0, 0, 0, 0}, {0, 0, 0, 0}, {0, 0, 0, 0}, {0, 0, 0, 0}};
      if (packed) {
#pragma unroll
        for (int mt = 0; mt < 4; ++mt)
#pragma unroll
          for (int kf = 0; kf < 4; ++kf)
            acc[mt] = __builtin_amdgcn_mfma_f32_16x16x32_f16(wA[mt * 4 + kf], bfX[kf],
                                                             acc[mt], 0, 0, 0);
#pragma unroll
        for (int mt = 0; mt < 4; ++mt)
#pragma unroll
          for (int kf = 0; kf < 4; ++kf)
            acc[mt] = __builtin_amdgcn_mfma_f32_16x16x32_f16(wB[mt * 4 + kf], bfH[kf],
                                                             acc[mt], 0, 0, 0);
      } else {
#pragma unroll
        for (int mt = 0; mt < 4; ++mt)
#pragma unroll
          for (int kf = 0; kf < 4; ++kf) {
            half8 a = cvt_frag(W_ih + (size_t)rowi[mt] * 128 + kf * 32 + k0b);
            acc[mt] = __builtin_amdgcn_mfma_f32_16x16x32_f16(a, bfX[kf], acc[mt], 0, 0, 0);
            half8 b = cvt_frag(W_hh + (size_t)rowi[mt] * 128 + kf * 32 + k0b);
            acc[mt] = __builtin_amdgcn_mfma_f32_16x16x32_f16(b, bfH[kf], acc[mt], 0, 0, 0);
          }
      }
      // ACT0
      _Float16 h4[4];
#pragma unroll
      for (int mt = 0; mt < 4; ++mt) {
        float si = sigm(acc[mt][0] + bb[mt][0]);
        float sf = sigm(acc[mt][1] + bb[mt][1]);
        float tg = tanh_f(acc[mt][2] + bb[mt][2]);
        float so = sigm(acc[mt][3] + bb[mt][3]);
        float cn = sf * c0[mt] + si * tg;
        float hn = so * tanh_f(cn);
        c0[mt] = mk ? cn : c0[mt];
        hp0[mt] = mk ? hn : hp0[mt];
        h4[mt] = (_Float16)hp0[mt];
      }
      *(half4v*)(sm + H0O + p * 4096 + OFF(lb, u0)) = *(half4v*)h4;
      if (packed) ISSUE_L(1);  // prefetch layer-1 frags across the barrier
    }
    BARRIER();  // h0[p] published; vmcnt NOT drained

    // stage x(t+1) into XT[p^1]
    if (doX) {
      half4v hx;
      hx[0] = (_Float16)xpre[0]; hx[1] = (_Float16)xpre[1];
      hx[2] = (_Float16)xpre[2]; hx[3] = (_Float16)xpre[3];
      *(half4v*)(sm + XTO + (p ^ 1) * 4096 + OFF(xb, xk4)) = hx;
    }

    // ================= layer 1 =================
    {
      const char* sX = sm + H0O + p * 4096;   // fresh h0(t)
      const char* sH = sm + H1O + p * 4096;   // h1(t-1)
      half8 bfX[4], bfH[4];
#pragma unroll
      for (int kf = 0; kf < 4; ++kf)
        bfX[kf] = *(const half8*)(sX + OFF(lb, kf * 32 + k0b));
#pragma unroll
      for (int kf = 0; kf < 4; ++kf)
        bfH[kf] = *(const half8*)(sH + OFF(lb, kf * 32 + k0b));
      f32x4 bb[4];
#pragma unroll
      for (int mt = 0; mt < 4; ++mt)
        bb[mt] = *(const f32x4*)(biasS + 512 + (u0 + mt) * 4);

      f32x4 acc[4] = {{0, 0, 0, 0}, {0, 0, 0, 0}, {0, 0, 0, 0}, {0, 0, 0, 0}};
      if (packed) {
#pragma unroll
        for (int mt = 0; mt < 4; ++mt)
#pragma unroll
          for (int kf = 0; kf < 4; ++kf)
            acc[mt] = __builtin_amdgcn_mfma_f32_16x16x32_f16(wA[mt * 4 + kf], bfX[kf],
                                                             acc[mt], 0, 0, 0);
#pragma unroll
        for (int mt = 0; mt < 4; ++mt)
#pragma unroll
          for (int kf = 0; kf < 4; ++kf)
            acc[mt] = __builtin_amdgcn_mfma_f32_16x16x32_f16(wB[mt * 4 + kf], bfH[kf],
                                                             acc[mt], 0, 0, 0);
      } else {
#pragma unroll
        for (int mt = 0; mt < 4; ++mt)
#pragma unroll
          for (int kf = 0; kf < 4; ++kf) {
            half8 a = cvt_frag(W_ih + (size_t)(512 + rowi[mt]) * 128 + kf * 32 + k0b);
            acc[mt] = __builtin_amdgcn_mfma_f32_16x16x32_f16(a, bfX[kf], acc[mt], 0, 0, 0);
            half8 b = cvt_frag(W_hh + (size_t)(512 + rowi[mt]) * 128 + kf * 32 + k0b);
            acc[mt] = __builtin_amdgcn_mfma_f32_16x16x32_f16(b, bfH[kf], acc[mt], 0, 0, 0);
          }
      }
      // ACT1 + output
      _Float16 h4[4];
      f32x4 vo;
#pragma unroll
      for (int mt = 0; mt < 4; ++mt) {
        float si = sigm(acc[mt][0] + bb[mt][0]);
        float sf = sigm(acc[mt][1] + bb[mt][1]);
        float tg = tanh_f(acc[mt][2] + bb[mt][2]);
        float so = sigm(acc[mt][3] + bb[mt][3]);
        float cn = sf * c1[mt] + si * tg;
        float hn = so * tanh_f(cn);
        c1[mt] = mk ? cn : c1[mt];
        hp1[mt] = mk ? hn : hp1[mt];
        h4[mt] = (_Float16)hp1[mt];
        vo[mt] = mk ? hn : 0.0f;
      }
      *(half4v*)(sm + H1O + (p ^ 1) * 4096 + OFF(lb, u0)) = *(half4v*)h4;
      size_t oix = (t < 200)
                       ? ((size_t)batch * 25600 + (size_t)t * 128 + u0)
                       : (13107200ull + (size_t)batch * 25600 + (size_t)(t - 200) * 128 + u0);
      *(f32x4*)(out + oix) = vo;
      if (packed) ISSUE_L(0);  // prefetch next step's layer-0 frags
    }
    BARRIER();  // h1[p^1], XT[p^1] published
  }
}

extern "C" void kernel_launch(void* const* d_in, const int* in_sizes, int n_in,
                              void* d_out, int out_size, void* d_ws, size_t ws_size,
                              hipStream_t stream) {
  (void)in_sizes; (void)n_in; (void)out_size;
  const float* x = (const float*)d_in[0];
  const int* len_in = (const int*)d_in[1];
  const int* len_ar = (const int*)d_in[2];
  // d_in[3] = mask_aureg (bool) unused; recomputed from lengths (monotone mask)
  const float* W_ih = (const float*)d_in[4];
  const float* W_hh = (const float*)d_in[5];
  const float* b_ih = (const float*)d_in[6];
  const float* b_hh = (const float*)d_in[7];
  float* out = (float*)d_out;
  char* ws = (char*)d_ws;

  int packed = (ws_size >= (size_t)524288) ? 1 : 0;
  if (packed) pack_kernel<<<dim3(128), dim3(256), 0, stream>>>(W_ih, W_hh, ws);
  lstm_kernel<<<dim3(32), dim3(512), 0, stream>>>(x, len_in, len_ar, W_ih, W_hh,
                                                  b_ih, b_hh, ws, out, packed);
}

// Round 4
// 1902.950 us; speedup vs baseline: 2.7475x; 2.7445x over previous
//
#include <hip/hip_runtime.h>
#include <hip/hip_fp16.h>

typedef _Float16 half8 __attribute__((ext_vector_type(8)));
typedef float f32x4 __attribute__((ext_vector_type(4)));

#define T_INS 200

// LDS layout (bytes)
constexpr int WI0O = 0;       // 128 KiB: W_ih[0] as MFMA A-fragments
constexpr int H0O  = 131072;  // 2 x 4096 (parity)
constexpr int H1O  = 139264;  // 2 x 4096
constexpr int XTO  = 147456;  // 2 x 4096
constexpr int BIO  = 155648;  // float[2][512] gate-interleaved biases
constexpr int SMSZ = 159744;  // 156 KiB total

// swizzled [batch][k(half)] f16 layout (2-way max bank aliasing on b128)
#define OFF(b, k) (((((b) << 8) | ((k) << 1))) ^ (((b) & 7) << 4))

// counted barrier: publish LDS only; global loads/stores stay in flight
#define BARRIER() asm volatile("s_waitcnt lgkmcnt(0)\n\ts_barrier" ::: "memory")

__device__ __forceinline__ float sigm(float x) {
  return __builtin_amdgcn_rcpf(1.0f + __builtin_amdgcn_exp2f(-1.44269504f * x));
}
__device__ __forceinline__ float tanh_f(float x) {
  return 1.0f - 2.0f * __builtin_amdgcn_rcpf(1.0f + __builtin_amdgcn_exp2f(2.88539008f * x));
}
__device__ __forceinline__ half8 cvt_frag(const float* __restrict__ src) {
  f32x4 a = *(const f32x4*)src;
  f32x4 b = *(const f32x4*)(src + 4);
  half8 h;
  h[0] = (_Float16)a[0]; h[1] = (_Float16)a[1]; h[2] = (_Float16)a[2]; h[3] = (_Float16)a[3];
  h[4] = (_Float16)b[0]; h[5] = (_Float16)b[1]; h[6] = (_Float16)b[2]; h[7] = (_Float16)b[3];
  return h;
}
__device__ __forceinline__ half8 cvt8(f32x4 a, f32x4 b) {
  half8 h;
  h[0] = (_Float16)a[0]; h[1] = (_Float16)a[1]; h[2] = (_Float16)a[2]; h[3] = (_Float16)a[3];
  h[4] = (_Float16)b[0]; h[5] = (_Float16)b[1]; h[6] = (_Float16)b[2]; h[7] = (_Float16)b[3];
  return h;
}
// permuted row: rp = w*128 + mt*16 + r  ->  orig_row = gate*128 + unit,
// gate = r&3, unit = w*32 + (r>>2)*8 + mt  (lane's 8 ACT units contiguous)
__device__ __forceinline__ int perm_row(int w, int mt, int r) {
  return (r & 3) * 128 + w * 32 + (r >> 2) * 8 + mt;
}

// Pack into ws: G 0..127 = W_ih[1], 128..255 = W_hh[0], 256..383 = W_hh[1].
// Frag F = (w*8+mt)*4 + kf ; 64 lanes x 16B.
__global__ __launch_bounds__(256) void pack_kernel(const float* __restrict__ W_ih,
                                                   const float* __restrict__ W_hh,
                                                   char* __restrict__ ws) {
  int gid = blockIdx.x * 256 + threadIdx.x;  // 24576 threads exactly
  int G = gid >> 6, lane = gid & 63;
  int region = G >> 7, F = G & 127;
  int w = F >> 5, mt = (F >> 2) & 7, kf = F & 3;
  int row = perm_row(w, mt, lane & 15);
  int k0 = kf * 32 + (lane >> 4) * 8;
  const float* src = (region == 0)
                         ? (W_ih + (size_t)(512 + row) * 128 + k0)
                         : (W_hh + (size_t)((region - 1) * 512 + row) * 128 + k0);
  *(half8*)(ws + (size_t)G * 1024 + lane * 16) = cvt_frag(src);
}

template <int PACKED>
__global__ __launch_bounds__(256, 1) void lstm_kernel(
    const float* __restrict__ x, const int* __restrict__ len_in,
    const int* __restrict__ len_ar, const float* __restrict__ W_ih,
    const float* __restrict__ W_hh, const float* __restrict__ b_ih,
    const float* __restrict__ b_hh, const char* __restrict__ ws,
    float* __restrict__ out) {
  __shared__ __attribute__((aligned(16))) char sm[SMSZ];
  float* biasS = (float*)(sm + BIO);

  const int tid = threadIdx.x;
  const int w = tid >> 6, lane = tid & 63;
  const int lb = lane & 15, lg = lane >> 4;
  const int k0b = lg * 8;
  const int u0 = w * 32 + lg * 8;  // lane's 8 contiguous units: u0..u0+7
  const int batch = blockIdx.x * 16 + lb;
  const int Lin = len_in[batch];
  const int Lar = len_ar[batch];

  // ---- one-time init ----
  // W_ih[0] -> LDS as frags (each thread fills 512B)
  for (int j = 0; j < 32; ++j) {
    int pos = tid * 512 + j * 16;
    int F = pos >> 10, ln = (pos >> 4) & 63;
    int fw = F >> 5, fmt = (F >> 2) & 7, fkf = F & 3;
    int row = perm_row(fw, fmt, ln & 15);
    int k0 = fkf * 32 + (ln >> 4) * 8;
    *(half8*)(sm + WI0O + pos) = cvt_frag(W_ih + (size_t)row * 128 + k0);
  }
  // gate-interleaved biases: biasS[l*512 + u*4 + q]
  for (int i = tid; i < 1024; i += 256) {
    int l = i >> 9, rp = i & 511, u = rp >> 2, q = rp & 3;
    biasS[i] = b_ih[l * 512 + q * 128 + u] + b_hh[l * 512 + q * 128 + u];
  }
  // zero h0/h1 (both parities)
#pragma unroll
  for (int i = 0; i < 4; ++i)
    *(f32x4*)(sm + H0O + tid * 16 + i * 4096) = (f32x4){0.f, 0.f, 0.f, 0.f};
  // x(t=0) -> XT[0]
  const int xb8 = tid >> 4, xk8 = (tid & 15) * 8;
  {
    const float* xp = x + ((size_t)(blockIdx.x * 16 + xb8) * T_INS) * 128 + xk8;
    *(half8*)(sm + XTO + OFF(xb8, xk8)) =
        cvt8(*(const f32x4*)xp, *(const f32x4*)(xp + 4));
  }

  // resident recurrent weights (loaded once; loop-invariant -> AGPR)
  half8 whh0[8][4], whh1[8][4];
  if (PACKED) {
    const char* base = ws + 131072 + (size_t)lane * 16;
#pragma unroll
    for (int mt = 0; mt < 8; ++mt)
#pragma unroll
      for (int kf = 0; kf < 4; ++kf) {
        whh0[mt][kf] = *(const half8*)(base + ((w * 8 + mt) * 4 + kf) * 1024);
        whh1[mt][kf] = *(const half8*)(base + 131072 + ((w * 8 + mt) * 4 + kf) * 1024);
      }
  } else {
#pragma unroll
    for (int mt = 0; mt < 8; ++mt)
#pragma unroll
      for (int kf = 0; kf < 4; ++kf) {
        int row = perm_row(w, mt, lb);
        whh0[mt][kf] = cvt_frag(W_hh + (size_t)row * 128 + kf * 32 + k0b);
        whh1[mt][kf] = cvt_frag(W_hh + (size_t)(512 + row) * 128 + kf * 32 + k0b);
      }
  }

  float c0[8], c1[8], hp0[8], hp1[8];
#pragma unroll
  for (int i = 0; i < 8; ++i) { c0[i] = c1[i] = hp0[i] = hp1[i] = 0.f; }
  __syncthreads();

  const char* wsl = ws + (size_t)lane * 16;  // region 0: W_ih[1] frags
  const half8* wi0 = (const half8*)(sm + WI0O);
  const int wi0b = w * 2048 + lane;  // frag f at wi0[wi0b + (mt*4+kf)*64]

#define LOAD_Q(dst, mtbase)                                                   \
  do {                                                                        \
    if (PACKED) {                                                             \
      _Pragma("unroll") for (int f = 0; f < 8; ++f)                           \
          dst[f] = *(const half8*)(wsl +                                      \
              ((w * 8 + (mtbase) + (f >> 2)) * 4 + (f & 3)) * 1024);          \
    } else {                                                                  \
      _Pragma("unroll") for (int f = 0; f < 8; ++f)                           \
          dst[f] = cvt_frag(W_ih +                                            \
              (size_t)(512 + perm_row(w, (mtbase) + (f >> 2), lb)) * 128 +    \
              (f & 3) * 32 + k0b);                                            \
    }                                                                         \
  } while (0)

  for (int t = 0; t < 400; ++t) {
    const int p = t & 1;
    const bool doX = (t < 199);
    f32x4 xpre0 = (f32x4){0.f, 0.f, 0.f, 0.f}, xpre1 = xpre0;
    if (doX) {
      const float* xp = x + ((size_t)(blockIdx.x * 16 + xb8) * T_INS + (t + 1)) * 128 + xk8;
      xpre0 = *(const f32x4*)xp;
      xpre1 = *(const f32x4*)(xp + 4);
    }
    const bool mk = (t < 200) ? (t < Lin) : ((t - 200) < Lar);

    // ================= layer 0 =================
    f32x4 acc[8];
#pragma unroll
    for (int i = 0; i < 8; ++i) acc[i] = (f32x4){0.f, 0.f, 0.f, 0.f};
    half8 wqA[8], wqB[8];
    {
      const char* sX = (t < 200) ? (sm + XTO + p * 4096) : (sm + H1O + p * 4096);
      const char* sH = sm + H0O + (p ^ 1) * 4096;
      half8 bfX[4], bfH[4];
#pragma unroll
      for (int kf = 0; kf < 4; ++kf) {
        bfX[kf] = *(const half8*)(sX + OFF(lb, kf * 32 + k0b));
        bfH[kf] = *(const half8*)(sH + OFF(lb, kf * 32 + k0b));
      }
      // resident hh first (no memory wait), then ih from LDS (pipelined)
#pragma unroll
      for (int mt = 0; mt < 8; ++mt)
#pragma unroll
        for (int kf = 0; kf < 4; ++kf)
          acc[mt] = __builtin_amdgcn_mfma_f32_16x16x32_f16(whh0[mt][kf], bfH[kf],
                                                           acc[mt], 0, 0, 0);
#pragma unroll
      for (int mt = 0; mt < 8; ++mt)
#pragma unroll
        for (int kf = 0; kf < 4; ++kf) {
          half8 a = wi0[wi0b + (mt * 4 + kf) * 64];
          acc[mt] = __builtin_amdgcn_mfma_f32_16x16x32_f16(a, bfX[kf], acc[mt], 0, 0, 0);
        }
      // prefetch W_ih[1] quarters for layer 1 (in flight across ACT0+barrier)
      LOAD_Q(wqA, 0);
      LOAD_Q(wqB, 2);
    }
    // ACT0
    {
      _Float16 h8[8];
#pragma unroll
      for (int mt = 0; mt < 8; ++mt) {
        f32x4 bb = *(const f32x4*)(biasS + (u0 + mt) * 4);
        float si = sigm(acc[mt][0] + bb[0]);
        float sf = sigm(acc[mt][1] + bb[1]);
        float tg = tanh_f(acc[mt][2] + bb[2]);
        float so = sigm(acc[mt][3] + bb[3]);
        float cn = sf * c0[mt] + si * tg;
        float hn = so * tanh_f(cn);
        c0[mt] = mk ? cn : c0[mt];
        hp0[mt] = mk ? hn : hp0[mt];
        h8[mt] = (_Float16)hp0[mt];
      }
      *(half8*)(sm + H0O + p * 4096 + OFF(lb, u0)) = *(half8*)h8;
    }
    BARRIER();  // h0[p] published; vmcnt stays counted

    // stage x(t+1) into XT[p^1]
    if (doX)
      *(half8*)(sm + XTO + (p ^ 1) * 4096 + OFF(xb8, xk8)) = cvt8(xpre0, xpre1);

    // ================= layer 1 =================
#pragma unroll
    for (int i = 0; i < 8; ++i) acc[i] = (f32x4){0.f, 0.f, 0.f, 0.f};
    {
      const char* sX = sm + H0O + p * 4096;  // fresh h0(t)
      const char* sH = sm + H1O + p * 4096;  // h1(t-1)
      half8 bfX[4], bfH[4];
#pragma unroll
      for (int kf = 0; kf < 4; ++kf) {
        bfX[kf] = *(const half8*)(sX + OFF(lb, kf * 32 + k0b));
        bfH[kf] = *(const half8*)(sH + OFF(lb, kf * 32 + k0b));
      }
#define L1_PAIR(m0, buf)                                                      \
  _Pragma("unroll") for (int j = 0; j < 2; ++j)                               \
      _Pragma("unroll") for (int kf = 0; kf < 4; ++kf)                        \
          acc[(m0) + j] = __builtin_amdgcn_mfma_f32_16x16x32_f16(             \
              whh1[(m0) + j][kf], bfH[kf], acc[(m0) + j], 0, 0, 0);           \
  _Pragma("unroll") for (int j = 0; j < 2; ++j)                               \
      _Pragma("unroll") for (int kf = 0; kf < 4; ++kf)                        \
          acc[(m0) + j] = __builtin_amdgcn_mfma_f32_16x16x32_f16(             \
              buf[j * 4 + kf], bfX[kf], acc[(m0) + j], 0, 0, 0);

      L1_PAIR(0, wqA)
      LOAD_Q(wqA, 4);  // reuse freed buffer; ~16 MFMAs ahead of use
      L1_PAIR(2, wqB)
      LOAD_Q(wqB, 6);
      L1_PAIR(4, wqA)
      L1_PAIR(6, wqB)
#undef L1_PAIR
    }
    // ACT1 + output
    {
      _Float16 h8[8];
      f32x4 vo0, vo1;
#pragma unroll
      for (int mt = 0; mt < 8; ++mt) {
        f32x4 bb = *(const f32x4*)(biasS + 512 + (u0 + mt) * 4);
        float si = sigm(acc[mt][0] + bb[0]);
        float sf = sigm(acc[mt][1] + bb[1]);
        float tg = tanh_f(acc[mt][2] + bb[2]);
        float so = sigm(acc[mt][3] + bb[3]);
        float cn = sf * c1[mt] + si * tg;
        float hn = so * tanh_f(cn);
        c1[mt] = mk ? cn : c1[mt];
        hp1[mt] = mk ? hn : hp1[mt];
        h8[mt] = (_Float16)hp1[mt];
        float v = mk ? hn : 0.0f;
        if (mt < 4) vo0[mt] = v; else vo1[mt - 4] = v;
      }
      *(half8*)(sm + H1O + (p ^ 1) * 4096 + OFF(lb, u0)) = *(half8*)h8;
      size_t oix = (t < 200)
                       ? ((size_t)batch * 25600 + (size_t)t * 128 + u0)
                       : (13107200ull + (size_t)batch * 25600 + (size_t)(t - 200) * 128 + u0);
      *(f32x4*)(out + oix) = vo0;
      *(f32x4*)(out + oix + 4) = vo1;
    }
    BARRIER();  // h1[p^1], XT[p^1] published
  }
#undef LOAD_Q
}

extern "C" void kernel_launch(void* const* d_in, const int* in_sizes, int n_in,
                              void* d_out, int out_size, void* d_ws, size_t ws_size,
                              hipStream_t stream) {
  (void)in_sizes; (void)n_in; (void)out_size;
  const float* x = (const float*)d_in[0];
  const int* len_in = (const int*)d_in[1];
  const int* len_ar = (const int*)d_in[2];
  // d_in[3] = mask_aureg unused (monotone mask recomputed from lengths)
  const float* W_ih = (const float*)d_in[4];
  const float* W_hh = (const float*)d_in[5];
  const float* b_ih = (const float*)d_in[6];
  const float* b_hh = (const float*)d_in[7];
  float* out = (float*)d_out;
  char* ws = (char*)d_ws;

  if (ws_size >= (size_t)393216) {
    pack_kernel<<<dim3(96), dim3(256), 0, stream>>>(W_ih, W_hh, ws);
    lstm_kernel<1><<<dim3(32), dim3(256), 0, stream>>>(x, len_in, len_ar, W_ih,
                                                       W_hh, b_ih, b_hh, ws, out);
  } else {
    lstm_kernel<0><<<dim3(32), dim3(256), 0, stream>>>(x, len_in, len_ar, W_ih,
                                                       W_hh, b_ih, b_hh, ws, out);
  }
}

// Round 5
// 1615.568 us; speedup vs baseline: 3.2363x; 1.1779x over previous
//
#include <hip/hip_runtime.h>
#include <hip/hip_fp16.h>

typedef _Float16 half8 __attribute__((ext_vector_type(8)));
typedef float f32x4 __attribute__((ext_vector_type(4)));

#define T_INS 200

// LDS layout (bytes)
constexpr int WI0O = 0;       // 128 KiB: W_ih[0] as MFMA A-fragments
constexpr int H0O  = 131072;  // 2 x 4096 (parity)
constexpr int H1O  = 139264;  // 2 x 4096
constexpr int XTO  = 147456;  // 2 x 4096
constexpr int BIO  = 155648;  // float[2][512] gate-interleaved biases
constexpr int SMSZ = 159744;  // 156 KiB total

// swizzled [batch][k(half)] f16 layout (2-way max bank aliasing on b128)
#define OFF(b, k) (((((b) << 8) | ((k) << 1))) ^ (((b) & 7) << 4))

// counted barrier: publish LDS only; global loads/stores stay in flight
#define BARRIER() asm volatile("s_waitcnt lgkmcnt(0)\n\ts_barrier" ::: "memory")

__device__ __forceinline__ float sigm(float x) {
  return __builtin_amdgcn_rcpf(1.0f + __builtin_amdgcn_exp2f(-1.44269504f * x));
}
__device__ __forceinline__ float tanh_f(float x) {
  return 1.0f - 2.0f * __builtin_amdgcn_rcpf(1.0f + __builtin_amdgcn_exp2f(2.88539008f * x));
}
__device__ __forceinline__ half8 cvt_frag(const float* __restrict__ src) {
  f32x4 a = *(const f32x4*)src;
  f32x4 b = *(const f32x4*)(src + 4);
  half8 h;
  h[0] = (_Float16)a[0]; h[1] = (_Float16)a[1]; h[2] = (_Float16)a[2]; h[3] = (_Float16)a[3];
  h[4] = (_Float16)b[0]; h[5] = (_Float16)b[1]; h[6] = (_Float16)b[2]; h[7] = (_Float16)b[3];
  return h;
}
__device__ __forceinline__ half8 cvt8(f32x4 a, f32x4 b) {
  half8 h;
  h[0] = (_Float16)a[0]; h[1] = (_Float16)a[1]; h[2] = (_Float16)a[2]; h[3] = (_Float16)a[3];
  h[4] = (_Float16)b[0]; h[5] = (_Float16)b[1]; h[6] = (_Float16)b[2]; h[7] = (_Float16)b[3];
  return h;
}
// permuted row: rp = w*128 + mt*16 + r  ->  orig_row = gate*128 + unit,
// gate = r&3, unit = w*32 + (r>>2)*8 + mt  (lane's 8 ACT units contiguous)
__device__ __forceinline__ int perm_row(int w, int mt, int r) {
  return (r & 3) * 128 + w * 32 + (r >> 2) * 8 + mt;
}

// Pack into ws: G 0..127 = W_ih[1], 128..255 = W_hh[0], 256..383 = W_hh[1].
// Frag F = (w*8+mt)*4 + kf ; 64 lanes x 16B.
__global__ __launch_bounds__(256) void pack_kernel(const float* __restrict__ W_ih,
                                                   const float* __restrict__ W_hh,
                                                   char* __restrict__ ws) {
  int gid = blockIdx.x * 256 + threadIdx.x;  // 24576 threads exactly
  int G = gid >> 6, lane = gid & 63;
  int region = G >> 7, F = G & 127;
  int w = F >> 5, mt = (F >> 2) & 7, kf = F & 3;
  int row = perm_row(w, mt, lane & 15);
  int k0 = kf * 32 + (lane >> 4) * 8;
  const float* src = (region == 0)
                         ? (W_ih + (size_t)(512 + row) * 128 + k0)
                         : (W_hh + (size_t)((region - 1) * 512 + row) * 128 + k0);
  *(half8*)(ws + (size_t)G * 1024 + lane * 16) = cvt_frag(src);
}

template <int PACKED>
__global__ __launch_bounds__(256, 1) void lstm_kernel(
    const float* __restrict__ x, const int* __restrict__ len_in,
    const int* __restrict__ len_ar, const float* __restrict__ W_ih,
    const float* __restrict__ W_hh, const float* __restrict__ b_ih,
    const float* __restrict__ b_hh, const char* __restrict__ ws,
    float* __restrict__ out) {
  __shared__ __attribute__((aligned(16))) char sm[SMSZ];
  float* biasS = (float*)(sm + BIO);

  const int tid = threadIdx.x;
  const int w = tid >> 6, lane = tid & 63;
  const int lb = lane & 15, lg = lane >> 4;
  const int k0b = lg * 8;
  const int u0 = w * 32 + lg * 8;  // lane's 8 contiguous units: u0..u0+7
  const int batch = blockIdx.x * 16 + lb;
  const int Lin = len_in[batch];
  const int Lar = len_ar[batch];

  // ---- one-time init ----
  // W_ih[0] -> LDS as frags (each thread fills 512B)
  for (int j = 0; j < 32; ++j) {
    int pos = tid * 512 + j * 16;
    int F = pos >> 10, ln = (pos >> 4) & 63;
    int fw = F >> 5, fmt = (F >> 2) & 7, fkf = F & 3;
    int row = perm_row(fw, fmt, ln & 15);
    int k0 = fkf * 32 + (ln >> 4) * 8;
    *(half8*)(sm + WI0O + pos) = cvt_frag(W_ih + (size_t)row * 128 + k0);
  }
  // gate-interleaved biases: biasS[l*512 + u*4 + q]
  for (int i = tid; i < 1024; i += 256) {
    int l = i >> 9, rp = i & 511, u = rp >> 2, q = rp & 3;
    biasS[i] = b_ih[l * 512 + q * 128 + u] + b_hh[l * 512 + q * 128 + u];
  }
  // zero h0/h1 (both parities)
#pragma unroll
  for (int i = 0; i < 4; ++i)
    *(f32x4*)(sm + H0O + tid * 16 + i * 4096) = (f32x4){0.f, 0.f, 0.f, 0.f};
  // x(t=0) -> XT[0]
  const int xb8 = tid >> 4, xk8 = (tid & 15) * 8;
  {
    const float* xp = x + ((size_t)(blockIdx.x * 16 + xb8) * T_INS) * 128 + xk8;
    *(half8*)(sm + XTO + OFF(xb8, xk8)) =
        cvt8(*(const f32x4*)xp, *(const f32x4*)(xp + 4));
  }

  // ALL recurrent + layer-1 input weights resident (384 regs: AGPR+VGPR).
  // Loaded once; zero per-step global weight traffic.
  half8 whh0[8][4], whh1[8][4], wi1[8][4];
  if (PACKED) {
    const char* base = ws + (size_t)lane * 16;
#pragma unroll
    for (int mt = 0; mt < 8; ++mt)
#pragma unroll
      for (int kf = 0; kf < 4; ++kf) {
        int fo = ((w * 8 + mt) * 4 + kf) * 1024;
        wi1[mt][kf]  = *(const half8*)(base + fo);
        whh0[mt][kf] = *(const half8*)(base + 131072 + fo);
        whh1[mt][kf] = *(const half8*)(base + 262144 + fo);
      }
  } else {
#pragma unroll
    for (int mt = 0; mt < 8; ++mt)
#pragma unroll
      for (int kf = 0; kf < 4; ++kf) {
        int row = perm_row(w, mt, lb);
        wi1[mt][kf]  = cvt_frag(W_ih + (size_t)(512 + row) * 128 + kf * 32 + k0b);
        whh0[mt][kf] = cvt_frag(W_hh + (size_t)row * 128 + kf * 32 + k0b);
        whh1[mt][kf] = cvt_frag(W_hh + (size_t)(512 + row) * 128 + kf * 32 + k0b);
      }
  }

  float c0[8], c1[8];
  half8 hp0v, hp1v;
#pragma unroll
  for (int i = 0; i < 8; ++i) { c0[i] = c1[i] = 0.f; hp0v[i] = (_Float16)0.f; hp1v[i] = (_Float16)0.f; }
  __syncthreads();

  const half8* wi0 = (const half8*)(sm + WI0O);
  const int wi0b = w * 2048 + lane;  // frag (mt,kf) at wi0[wi0b + (mt*4+kf)*64]

  for (int t = 0; t < 400; ++t) {
    const int p = t & 1;
    const bool doX = (t < 199);
    f32x4 xpre0 = (f32x4){0.f, 0.f, 0.f, 0.f}, xpre1 = xpre0;
    if (doX) {
      const float* xp = x + ((size_t)(blockIdx.x * 16 + xb8) * T_INS + (t + 1)) * 128 + xk8;
      xpre0 = *(const f32x4*)xp;
      xpre1 = *(const f32x4*)(xp + 4);
    }
    const bool mk = (t < 200) ? (t < Lin) : ((t - 200) < Lar);

    // ================= layer 0 =================
    f32x4 acc[8];
    {
      const char* sX = (t < 200) ? (sm + XTO + p * 4096) : (sm + H1O + p * 4096);
      const char* sH = sm + H0O + (p ^ 1) * 4096;
      half8 bfX[4], bfH[4];
#pragma unroll
      for (int kf = 0; kf < 4; ++kf) {
        bfX[kf] = *(const half8*)(sX + OFF(lb, kf * 32 + k0b));
        bfH[kf] = *(const half8*)(sH + OFF(lb, kf * 32 + k0b));
      }
      // acc starts at the bias vector (gates of unit u0+mt for batch lb)
#pragma unroll
      for (int mt = 0; mt < 8; ++mt)
        acc[mt] = *(const f32x4*)(biasS + (u0 + mt) * 4);
      // resident hh first (no memory wait), then ih from LDS (pipelined)
#pragma unroll
      for (int mt = 0; mt < 8; ++mt)
#pragma unroll
        for (int kf = 0; kf < 4; ++kf)
          acc[mt] = __builtin_amdgcn_mfma_f32_16x16x32_f16(whh0[mt][kf], bfH[kf],
                                                           acc[mt], 0, 0, 0);
#pragma unroll
      for (int mt = 0; mt < 8; ++mt)
#pragma unroll
        for (int kf = 0; kf < 4; ++kf) {
          half8 a = wi0[wi0b + (mt * 4 + kf) * 64];
          acc[mt] = __builtin_amdgcn_mfma_f32_16x16x32_f16(a, bfX[kf], acc[mt], 0, 0, 0);
        }
    }
    // ACT0
    {
      _Float16 h8[8];
#pragma unroll
      for (int mt = 0; mt < 8; ++mt) {
        float si = sigm(acc[mt][0]);
        float sf = sigm(acc[mt][1]);
        float tg = tanh_f(acc[mt][2]);
        float so = sigm(acc[mt][3]);
        float cn = sf * c0[mt] + si * tg;
        float hn = so * tanh_f(cn);
        c0[mt] = mk ? cn : c0[mt];
        h8[mt] = (_Float16)hn;
      }
      hp0v = mk ? *(half8*)h8 : hp0v;
      *(half8*)(sm + H0O + p * 4096 + OFF(lb, u0)) = hp0v;
    }
    BARRIER();  // h0[p] published; vmcnt stays counted

    // stage x(t+1) into XT[p^1]
    if (doX)
      *(half8*)(sm + XTO + (p ^ 1) * 4096 + OFF(xb8, xk8)) = cvt8(xpre0, xpre1);

    // ================= layer 1 =================
    {
      const char* sX = sm + H0O + p * 4096;  // fresh h0(t)
      const char* sH = sm + H1O + p * 4096;  // h1(t-1)
      half8 bfX[4], bfH[4];
#pragma unroll
      for (int kf = 0; kf < 4; ++kf) {
        bfX[kf] = *(const half8*)(sX + OFF(lb, kf * 32 + k0b));
        bfH[kf] = *(const half8*)(sH + OFF(lb, kf * 32 + k0b));
      }
#pragma unroll
      for (int mt = 0; mt < 8; ++mt)
        acc[mt] = *(const f32x4*)(biasS + 512 + (u0 + mt) * 4);
#pragma unroll
      for (int mt = 0; mt < 8; ++mt)
#pragma unroll
        for (int kf = 0; kf < 4; ++kf)
          acc[mt] = __builtin_amdgcn_mfma_f32_16x16x32_f16(whh1[mt][kf], bfH[kf],
                                                           acc[mt], 0, 0, 0);
#pragma unroll
      for (int mt = 0; mt < 8; ++mt)
#pragma unroll
        for (int kf = 0; kf < 4; ++kf)
          acc[mt] = __builtin_amdgcn_mfma_f32_16x16x32_f16(wi1[mt][kf], bfX[kf],
                                                           acc[mt], 0, 0, 0);
    }
    // ACT1 + output
    {
      _Float16 h8[8];
      f32x4 vo0, vo1;
#pragma unroll
      for (int mt = 0; mt < 8; ++mt) {
        float si = sigm(acc[mt][0]);
        float sf = sigm(acc[mt][1]);
        float tg = tanh_f(acc[mt][2]);
        float so = sigm(acc[mt][3]);
        float cn = sf * c1[mt] + si * tg;
        float hn = so * tanh_f(cn);
        c1[mt] = mk ? cn : c1[mt];
        h8[mt] = (_Float16)hn;
        float v = mk ? hn : 0.0f;
        if (mt < 4) vo0[mt] = v; else vo1[mt - 4] = v;
      }
      hp1v = mk ? *(half8*)h8 : hp1v;
      *(half8*)(sm + H1O + (p ^ 1) * 4096 + OFF(lb, u0)) = hp1v;
      size_t oix = (t < 200)
                       ? ((size_t)batch * 25600 + (size_t)t * 128 + u0)
                       : (13107200ull + (size_t)batch * 25600 + (size_t)(t - 200) * 128 + u0);
      *(f32x4*)(out + oix) = vo0;
      *(f32x4*)(out + oix + 4) = vo1;
    }
    BARRIER();  // h1[p^1], XT[p^1] published
  }
}

extern "C" void kernel_launch(void* const* d_in, const int* in_sizes, int n_in,
                              void* d_out, int out_size, void* d_ws, size_t ws_size,
                              hipStream_t stream) {
  (void)in_sizes; (void)n_in; (void)out_size;
  const float* x = (const float*)d_in[0];
  const int* len_in = (const int*)d_in[1];
  const int* len_ar = (const int*)d_in[2];
  // d_in[3] = mask_aureg unused (monotone mask recomputed from lengths)
  const float* W_ih = (const float*)d_in[4];
  const float* W_hh = (const float*)d_in[5];
  const float* b_ih = (const float*)d_in[6];
  const float* b_hh = (const float*)d_in[7];
  float* out = (float*)d_out;
  char* ws = (char*)d_ws;

  if (ws_size >= (size_t)393216) {
    pack_kernel<<<dim3(96), dim3(256), 0, stream>>>(W_ih, W_hh, ws);
    lstm_kernel<1><<<dim3(32), dim3(256), 0, stream>>>(x, len_in, len_ar, W_ih,
                                                       W_hh, b_ih, b_hh, ws, out);
  } else {
    lstm_kernel<0><<<dim3(32), dim3(256), 0, stream>>>(x, len_in, len_ar, W_ih,
                                                       W_hh, b_ih, b_hh, ws, out);
  }
}

// Round 6
// 1545.647 us; speedup vs baseline: 3.3827x; 1.0452x over previous
//
#include <hip/hip_runtime.h>
#include <hip/hip_fp16.h>

typedef _Float16 half8 __attribute__((ext_vector_type(8)));
typedef float f32x4 __attribute__((ext_vector_type(4)));

#define T_INS 200

// LDS layout (bytes)
constexpr int WI0O = 0;       // 128 KiB: W_ih[0] as MFMA A-fragments
constexpr int H0O  = 131072;  // 2 x 4096 (parity)
constexpr int H1O  = 139264;  // 2 x 4096
constexpr int XTO  = 147456;  // 2 x 4096
constexpr int BIO  = 155648;  // float[2][512] gate-interleaved biases
constexpr int SMSZ = 159744;  // 156 KiB total

// swizzled [batch][k(half)] f16 layout (2-way max bank aliasing on b128)
#define OFF(b, k) (((((b) << 8) | ((k) << 1))) ^ (((b) & 7) << 4))

// counted barrier: publish LDS only; global loads/stores stay in flight
#define BARRIER() asm volatile("s_waitcnt lgkmcnt(0)\n\ts_barrier" ::: "memory")

__device__ __forceinline__ float sigm(float x) {
  return __builtin_amdgcn_rcpf(1.0f + __builtin_amdgcn_exp2f(-1.44269504f * x));
}
__device__ __forceinline__ float tanh_f(float x) {
  return 1.0f - 2.0f * __builtin_amdgcn_rcpf(1.0f + __builtin_amdgcn_exp2f(2.88539008f * x));
}
__device__ __forceinline__ half8 cvt_frag(const float* __restrict__ src) {
  f32x4 a = *(const f32x4*)src;
  f32x4 b = *(const f32x4*)(src + 4);
  half8 h;
  h[0] = (_Float16)a[0]; h[1] = (_Float16)a[1]; h[2] = (_Float16)a[2]; h[3] = (_Float16)a[3];
  h[4] = (_Float16)b[0]; h[5] = (_Float16)b[1]; h[6] = (_Float16)b[2]; h[7] = (_Float16)b[3];
  return h;
}
__device__ __forceinline__ half8 cvt8(f32x4 a, f32x4 b) {
  half8 h;
  h[0] = (_Float16)a[0]; h[1] = (_Float16)a[1]; h[2] = (_Float16)a[2]; h[3] = (_Float16)a[3];
  h[4] = (_Float16)b[0]; h[5] = (_Float16)b[1]; h[6] = (_Float16)b[2]; h[7] = (_Float16)b[3];
  return h;
}
// permuted row: rp = w*128 + mt*16 + r  ->  orig_row = gate*128 + unit,
// gate = r&3, unit = w*32 + (r>>2)*8 + mt  (lane's 8 ACT units contiguous)
__device__ __forceinline__ int perm_row(int w, int mt, int r) {
  return (r & 3) * 128 + w * 32 + (r >> 2) * 8 + mt;
}

// Pack into ws: G 0..127 = W_ih[1], 128..255 = W_hh[0], 256..383 = W_hh[1].
// Frag F = (w*8+mt)*4 + kf ; 64 lanes x 16B.
__global__ __launch_bounds__(256) void pack_kernel(const float* __restrict__ W_ih,
                                                   const float* __restrict__ W_hh,
                                                   char* __restrict__ ws) {
  int gid = blockIdx.x * 256 + threadIdx.x;  // 24576 threads exactly
  int G = gid >> 6, lane = gid & 63;
  int region = G >> 7, F = G & 127;
  int w = F >> 5, mt = (F >> 2) & 7, kf = F & 3;
  int row = perm_row(w, mt, lane & 15);
  int k0 = kf * 32 + (lane >> 4) * 8;
  const float* src = (region == 0)
                         ? (W_ih + (size_t)(512 + row) * 128 + k0)
                         : (W_hh + (size_t)((region - 1) * 512 + row) * 128 + k0);
  *(half8*)(ws + (size_t)G * 1024 + lane * 16) = cvt_frag(src);
}

template <int PACKED>
__global__ __launch_bounds__(256, 1) void lstm_kernel(
    const float* __restrict__ x, const int* __restrict__ len_in,
    const int* __restrict__ len_ar, const float* __restrict__ W_ih,
    const float* __restrict__ W_hh, const float* __restrict__ b_ih,
    const float* __restrict__ b_hh, const char* __restrict__ ws,
    float* __restrict__ out) {
  __shared__ __attribute__((aligned(16))) char sm[SMSZ];
  float* biasS = (float*)(sm + BIO);

  const int tid = threadIdx.x;
  const int w = tid >> 6, lane = tid & 63;
  const int lb = lane & 15, lg = lane >> 4;
  const int k0b = lg * 8;
  const int u0 = w * 32 + lg * 8;  // lane's 8 contiguous units: u0..u0+7
  const int batch = blockIdx.x * 16 + lb;
  const int Lin = len_in[batch];
  const int Lar = len_ar[batch];

  // ---- one-time init ----
  // W_ih[0] -> LDS as frags (each thread fills 512B)
  for (int j = 0; j < 32; ++j) {
    int pos = tid * 512 + j * 16;
    int F = pos >> 10, ln = (pos >> 4) & 63;
    int fw = F >> 5, fmt = (F >> 2) & 7, fkf = F & 3;
    int row = perm_row(fw, fmt, ln & 15);
    int k0 = fkf * 32 + (ln >> 4) * 8;
    *(half8*)(sm + WI0O + pos) = cvt_frag(W_ih + (size_t)row * 128 + k0);
  }
  // gate-interleaved biases: biasS[l*512 + u*4 + q]
  for (int i = tid; i < 1024; i += 256) {
    int l = i >> 9, rp = i & 511, u = rp >> 2, q = rp & 3;
    biasS[i] = b_ih[l * 512 + q * 128 + u] + b_hh[l * 512 + q * 128 + u];
  }
  // zero h0/h1 (both parities)
#pragma unroll
  for (int i = 0; i < 4; ++i)
    *(f32x4*)(sm + H0O + tid * 16 + i * 4096) = (f32x4){0.f, 0.f, 0.f, 0.f};
  // x(t=0) -> XT[0]
  const int xb8 = tid >> 4, xk8 = (tid & 15) * 8;
  {
    const float* xp = x + ((size_t)(blockIdx.x * 16 + xb8) * T_INS) * 128 + xk8;
    *(half8*)(sm + XTO + OFF(xb8, xk8)) =
        cvt8(*(const f32x4*)xp, *(const f32x4*)(xp + 4));
  }

  // ALL recurrent + layer-1 input weights resident (384 regs: AGPR+VGPR).
  half8 whh0[8][4], whh1[8][4], wi1[8][4];
  if (PACKED) {
    const char* base = ws + (size_t)lane * 16;
#pragma unroll
    for (int mt = 0; mt < 8; ++mt)
#pragma unroll
      for (int kf = 0; kf < 4; ++kf) {
        int fo = ((w * 8 + mt) * 4 + kf) * 1024;
        wi1[mt][kf]  = *(const half8*)(base + fo);
        whh0[mt][kf] = *(const half8*)(base + 131072 + fo);
        whh1[mt][kf] = *(const half8*)(base + 262144 + fo);
      }
  } else {
#pragma unroll
    for (int mt = 0; mt < 8; ++mt)
#pragma unroll
      for (int kf = 0; kf < 4; ++kf) {
        int row = perm_row(w, mt, lb);
        wi1[mt][kf]  = cvt_frag(W_ih + (size_t)(512 + row) * 128 + kf * 32 + k0b);
        whh0[mt][kf] = cvt_frag(W_hh + (size_t)row * 128 + kf * 32 + k0b);
        whh1[mt][kf] = cvt_frag(W_hh + (size_t)(512 + row) * 128 + kf * 32 + k0b);
      }
  }

  float c0[8], c1[8];
  half8 hp0v, hp1v;
#pragma unroll
  for (int i = 0; i < 8; ++i) { c0[i] = c1[i] = 0.f; hp0v[i] = (_Float16)0.f; hp1v[i] = (_Float16)0.f; }
  __syncthreads();

  const half8* wi0 = (const half8*)(sm + WI0O);
  const int wi0b = w * 2048 + lane;  // frag (mt,kf) at wi0[wi0b + (mt*4+kf)*64]

  for (int t = 0; t < 400; ++t) {
    const int p = t & 1;
    const bool doX = (t < 199);
    f32x4 xpre0 = (f32x4){0.f, 0.f, 0.f, 0.f}, xpre1 = xpre0;
    if (doX) {
      const float* xp = x + ((size_t)(blockIdx.x * 16 + xb8) * T_INS + (t + 1)) * 128 + xk8;
      xpre0 = *(const f32x4*)xp;
      xpre1 = *(const f32x4*)(xp + 4);
    }
    const bool mk = (t < 200) ? (t < Lin) : ((t - 200) < Lar);

    // ================= layer 0 =================
    f32x4 acc[8];
    {
      const char* sX = (t < 200) ? (sm + XTO + p * 4096) : (sm + H1O + p * 4096);
      const char* sH = sm + H0O + (p ^ 1) * 4096;
      half8 bfX[4], bfH[4];
#pragma unroll
      for (int kf = 0; kf < 4; ++kf) {
        bfX[kf] = *(const half8*)(sX + OFF(lb, kf * 32 + k0b));
        bfH[kf] = *(const half8*)(sH + OFF(lb, kf * 32 + k0b));
      }
      // acc starts at the bias vector (gates of unit u0+mt for batch lb)
#pragma unroll
      for (int mt = 0; mt < 8; ++mt)
        acc[mt] = *(const f32x4*)(biasS + (u0 + mt) * 4);
      // kf-outer / mt-inner: consecutive MFMAs hit different acc chains
      // (distance 8 between same-acc ops -> matrix pipe streams at ~5 cyc/op
      //  instead of paying ~16-cyc dependent latency each).
#pragma unroll
      for (int kf = 0; kf < 4; ++kf)
#pragma unroll
        for (int mt = 0; mt < 8; ++mt)
          acc[mt] = __builtin_amdgcn_mfma_f32_16x16x32_f16(whh0[mt][kf], bfH[kf],
                                                           acc[mt], 0, 0, 0);
#pragma unroll
      for (int kf = 0; kf < 4; ++kf)
#pragma unroll
        for (int mt = 0; mt < 8; ++mt) {
          half8 a = wi0[wi0b + (mt * 4 + kf) * 64];
          acc[mt] = __builtin_amdgcn_mfma_f32_16x16x32_f16(a, bfX[kf], acc[mt], 0, 0, 0);
        }
    }
    // ACT0
    {
      _Float16 h8[8];
#pragma unroll
      for (int mt = 0; mt < 8; ++mt) {
        float si = sigm(acc[mt][0]);
        float sf = sigm(acc[mt][1]);
        float tg = tanh_f(acc[mt][2]);
        float so = sigm(acc[mt][3]);
        float cn = sf * c0[mt] + si * tg;
        float hn = so * tanh_f(cn);
        c0[mt] = mk ? cn : c0[mt];
        h8[mt] = (_Float16)hn;
      }
      hp0v = mk ? *(half8*)h8 : hp0v;
      *(half8*)(sm + H0O + p * 4096 + OFF(lb, u0)) = hp0v;
    }
    BARRIER();  // h0[p] published; vmcnt stays counted

    // stage x(t+1) into XT[p^1]
    if (doX)
      *(half8*)(sm + XTO + (p ^ 1) * 4096 + OFF(xb8, xk8)) = cvt8(xpre0, xpre1);

    // ================= layer 1 =================
    {
      const char* sX = sm + H0O + p * 4096;  // fresh h0(t)
      const char* sH = sm + H1O + p * 4096;  // h1(t-1)
      half8 bfX[4], bfH[4];
#pragma unroll
      for (int kf = 0; kf < 4; ++kf) {
        bfX[kf] = *(const half8*)(sX + OFF(lb, kf * 32 + k0b));
        bfH[kf] = *(const half8*)(sH + OFF(lb, kf * 32 + k0b));
      }
#pragma unroll
      for (int mt = 0; mt < 8; ++mt)
        acc[mt] = *(const f32x4*)(biasS + 512 + (u0 + mt) * 4);
#pragma unroll
      for (int kf = 0; kf < 4; ++kf)
#pragma unroll
        for (int mt = 0; mt < 8; ++mt)
          acc[mt] = __builtin_amdgcn_mfma_f32_16x16x32_f16(whh1[mt][kf], bfH[kf],
                                                           acc[mt], 0, 0, 0);
#pragma unroll
      for (int kf = 0; kf < 4; ++kf)
#pragma unroll
        for (int mt = 0; mt < 8; ++mt)
          acc[mt] = __builtin_amdgcn_mfma_f32_16x16x32_f16(wi1[mt][kf], bfX[kf],
                                                           acc[mt], 0, 0, 0);
    }
    // ACT1 + output
    {
      _Float16 h8[8];
      f32x4 vo0, vo1;
#pragma unroll
      for (int mt = 0; mt < 8; ++mt) {
        float si = sigm(acc[mt][0]);
        float sf = sigm(acc[mt][1]);
        float tg = tanh_f(acc[mt][2]);
        float so = sigm(acc[mt][3]);
        float cn = sf * c1[mt] + si * tg;
        float hn = so * tanh_f(cn);
        c1[mt] = mk ? cn : c1[mt];
        h8[mt] = (_Float16)hn;
        float v = mk ? hn : 0.0f;
        if (mt < 4) vo0[mt] = v; else vo1[mt - 4] = v;
      }
      hp1v = mk ? *(half8*)h8 : hp1v;
      *(half8*)(sm + H1O + (p ^ 1) * 4096 + OFF(lb, u0)) = hp1v;
      size_t oix = (t < 200)
                       ? ((size_t)batch * 25600 + (size_t)t * 128 + u0)
                       : (13107200ull + (size_t)batch * 25600 + (size_t)(t - 200) * 128 + u0);
      *(f32x4*)(out + oix) = vo0;
      *(f32x4*)(out + oix + 4) = vo1;
    }
    BARRIER();  // h1[p^1], XT[p^1] published
  }
}

extern "C" void kernel_launch(void* const* d_in, const int* in_sizes, int n_in,
                              void* d_out, int out_size, void* d_ws, size_t ws_size,
                              hipStream_t stream) {
  (void)in_sizes; (void)n_in; (void)out_size;
  const float* x = (const float*)d_in[0];
  const int* len_in = (const int*)d_in[1];
  const int* len_ar = (const int*)d_in[2];
  // d_in[3] = mask_aureg unused (monotone mask recomputed from lengths)
  const float* W_ih = (const float*)d_in[4];
  const float* W_hh = (const float*)d_in[5];
  const float* b_ih = (const float*)d_in[6];
  const float* b_hh = (const float*)d_in[7];
  float* out = (float*)d_out;
  char* ws = (char*)d_ws;

  if (ws_size >= (size_t)393216) {
    pack_kernel<<<dim3(96), dim3(256), 0, stream>>>(W_ih, W_hh, ws);
    lstm_kernel<1><<<dim3(32), dim3(256), 0, stream>>>(x, len_in, len_ar, W_ih,
                                                       W_hh, b_ih, b_hh, ws, out);
  } else {
    lstm_kernel<0><<<dim3(32), dim3(256), 0, stream>>>(x, len_in, len_ar, W_ih,
                                                       W_hh, b_ih, b_hh, ws, out);
  }
}

// Round 7
// 1139.020 us; speedup vs baseline: 4.5903x; 1.3570x over previous
//
#include <hip/hip_runtime.h>
#include <hip/hip_fp16.h>

typedef _Float16 half8 __attribute__((ext_vector_type(8)));
typedef _Float16 half4v __attribute__((ext_vector_type(4)));
typedef float f32x4 __attribute__((ext_vector_type(4)));

#define T_INS 200

// LDS layout (bytes)
constexpr int WI0O = 0;       // 128 KiB: W_ih[0] as MFMA A-fragments
constexpr int H0O  = 131072;  // 2 x 4096 (parity)
constexpr int H1O  = 139264;  // 2 x 4096
constexpr int XTO  = 147456;  // 2 x 4096
constexpr int BIO  = 155648;  // float[2][512] gate-interleaved biases
constexpr int SMSZ = 159744;  // 156 KiB total

// swizzled [batch][k(half)] f16 layout (2-way max bank aliasing on b128)
#define OFF(b, k) (((((b) << 8) | ((k) << 1))) ^ (((b) & 7) << 4))

// counted barrier: publish LDS only; global loads/stores stay in flight
#define BARRIER() asm volatile("s_waitcnt lgkmcnt(0)\n\ts_barrier" ::: "memory")

__device__ __forceinline__ float sigm(float x) {
  return __builtin_amdgcn_rcpf(1.0f + __builtin_amdgcn_exp2f(-1.44269504f * x));
}
__device__ __forceinline__ float tanh_f(float x) {
  return 1.0f - 2.0f * __builtin_amdgcn_rcpf(1.0f + __builtin_amdgcn_exp2f(2.88539008f * x));
}
__device__ __forceinline__ half8 cvt_frag(const float* __restrict__ src) {
  f32x4 a = *(const f32x4*)src;
  f32x4 b = *(const f32x4*)(src + 4);
  half8 h;
  h[0] = (_Float16)a[0]; h[1] = (_Float16)a[1]; h[2] = (_Float16)a[2]; h[3] = (_Float16)a[3];
  h[4] = (_Float16)b[0]; h[5] = (_Float16)b[1]; h[6] = (_Float16)b[2]; h[7] = (_Float16)b[3];
  return h;
}
// 8-wave row permutation: gate = r&3, unit = w*16 + (r>>2)*4 + mt
__device__ __forceinline__ int perm_row8(int w, int mt, int r) {
  return (r & 3) * 128 + w * 16 + (r >> 2) * 4 + mt;
}

// Pack into ws: region 0 = W_ih[1], 1 = W_hh[0], 2 = W_hh[1] (128 KiB each).
// Frag F = w*16 + mt*4 + kf (w in [0,8), mt in [0,4)); 64 lanes x 16B.
__global__ __launch_bounds__(256) void pack_kernel(const float* __restrict__ W_ih,
                                                   const float* __restrict__ W_hh,
                                                   char* __restrict__ ws) {
  int gid = blockIdx.x * 256 + threadIdx.x;  // 24576 threads exactly
  int G = gid >> 6, lane = gid & 63;
  int region = G >> 7, F = G & 127;
  int w = F >> 4, mt = (F >> 2) & 3, kf = F & 3;
  int row = perm_row8(w, mt, lane & 15);
  int k0 = kf * 32 + (lane >> 4) * 8;
  const float* src = (region == 0)
                         ? (W_ih + (size_t)(512 + row) * 128 + k0)
                         : (W_hh + (size_t)((region - 1) * 512 + row) * 128 + k0);
  *(half8*)(ws + (size_t)G * 1024 + lane * 16) = cvt_frag(src);
}

template <int PACKED>
__global__ __launch_bounds__(512, 2) void lstm_kernel(
    const float* __restrict__ x, const int* __restrict__ len_in,
    const int* __restrict__ len_ar, const float* __restrict__ W_ih,
    const float* __restrict__ W_hh, const float* __restrict__ b_ih,
    const float* __restrict__ b_hh, const char* __restrict__ ws,
    float* __restrict__ out) {
  __shared__ __attribute__((aligned(16))) char sm[SMSZ];
  float* biasS = (float*)(sm + BIO);

  const int tid = threadIdx.x;
  const int w = tid >> 6, lane = tid & 63;
  const int lb = lane & 15, lg = lane >> 4;
  const int k0b = lg * 8;
  const int u0 = w * 16 + lg * 4;  // lane's 4 contiguous units: u0..u0+3
  const int batch = blockIdx.x * 16 + lb;
  const int Lin = len_in[batch];
  const int Lar = len_ar[batch];

  // ---- one-time init ----
  // W_ih[0] -> LDS as frags (each thread fills 256B)
  for (int j = 0; j < 16; ++j) {
    int pos = tid * 256 + j * 16;
    int F = pos >> 10, ln = (pos >> 4) & 63;
    int fw = F >> 4, fmt = (F >> 2) & 3, fkf = F & 3;
    int row = perm_row8(fw, fmt, ln & 15);
    int k0 = fkf * 32 + (ln >> 4) * 8;
    *(half8*)(sm + WI0O + pos) = cvt_frag(W_ih + (size_t)row * 128 + k0);
  }
  // gate-interleaved biases: biasS[l*512 + u*4 + q]
  for (int i = tid; i < 1024; i += 512) {
    int l = i >> 9, rp = i & 511, u = rp >> 2, q = rp & 3;
    biasS[i] = b_ih[l * 512 + q * 128 + u] + b_hh[l * 512 + q * 128 + u];
  }
  // zero h0/h1 (both parities): 16 KiB, 512 threads x 16B x 2
#pragma unroll
  for (int i = 0; i < 2; ++i)
    *(f32x4*)(sm + H0O + tid * 16 + i * 8192) = (f32x4){0.f, 0.f, 0.f, 0.f};
  // x(t=0) -> XT[0]: 512 threads, each 4 floats
  const int xb = tid >> 5, xk4 = (tid & 31) * 4;
  {
    f32x4 v = *(const f32x4*)(x + ((size_t)(blockIdx.x * 16 + xb) * T_INS) * 128 + xk4);
    half4v hx;
    hx[0] = (_Float16)v[0]; hx[1] = (_Float16)v[1];
    hx[2] = (_Float16)v[2]; hx[3] = (_Float16)v[3];
    *(half4v*)(sm + XTO + OFF(xb, xk4)) = hx;
  }

  // resident weights: 48 half8 = 192 regs/wave (wave w's 4 mt-tiles)
  half8 whh0[4][4], whh1[4][4], wi1[4][4];
  if (PACKED) {
    const char* base = ws + (size_t)lane * 16;
#pragma unroll
    for (int mt = 0; mt < 4; ++mt)
#pragma unroll
      for (int kf = 0; kf < 4; ++kf) {
        int fo = (w * 16 + mt * 4 + kf) * 1024;
        wi1[mt][kf]  = *(const half8*)(base + fo);
        whh0[mt][kf] = *(const half8*)(base + 131072 + fo);
        whh1[mt][kf] = *(const half8*)(base + 262144 + fo);
      }
  } else {
#pragma unroll
    for (int mt = 0; mt < 4; ++mt)
#pragma unroll
      for (int kf = 0; kf < 4; ++kf) {
        int row = perm_row8(w, mt, lb);
        wi1[mt][kf]  = cvt_frag(W_ih + (size_t)(512 + row) * 128 + kf * 32 + k0b);
        whh0[mt][kf] = cvt_frag(W_hh + (size_t)row * 128 + kf * 32 + k0b);
        whh1[mt][kf] = cvt_frag(W_hh + (size_t)(512 + row) * 128 + kf * 32 + k0b);
      }
  }

  float c0[4], c1[4];
  half4v hp0v, hp1v;
#pragma unroll
  for (int i = 0; i < 4; ++i) {
    c0[i] = c1[i] = 0.f;
    hp0v[i] = (_Float16)0.f; hp1v[i] = (_Float16)0.f;
  }
  __syncthreads();

  // strength-reduced pointers
  const float* xptr = x + ((size_t)(blockIdx.x * 16 + xb) * T_INS + 1) * 128 + xk4;
  float* optr = out + (size_t)batch * 25600 + u0;
  const size_t obase_ar = 13107200ull + (size_t)batch * 25600 + u0;
  const char* wi0base = sm + WI0O + w * 16384 + lane * 16;  // frag (mt,kf) at +(mt*4+kf)*1024

  for (int t = 0; t < 400; ++t) {
    const int p = t & 1;
    const bool doX = (t < 199);
    f32x4 xpre = (f32x4){0.f, 0.f, 0.f, 0.f};
    if (doX) { xpre = *(const f32x4*)xptr; xptr += 128; }
    const bool mk = (t < 200) ? (t < Lin) : ((t - 200) < Lar);

    // ================= layer 0 =================
    f32x4 acc[4];
    {
      const char* sX = (t < 200) ? (sm + XTO + p * 4096) : (sm + H1O + p * 4096);
      const char* sH = sm + H0O + (p ^ 1) * 4096;
      half8 bf[4];
      // acc starts at bias vector
#pragma unroll
      for (int mt = 0; mt < 4; ++mt)
        acc[mt] = *(const f32x4*)(biasS + (u0 + mt) * 4);
      // hh (resident) first
#pragma unroll
      for (int kf = 0; kf < 4; ++kf)
        bf[kf] = *(const half8*)(sH + OFF(lb, kf * 32 + k0b));
#pragma unroll
      for (int kf = 0; kf < 4; ++kf)
#pragma unroll
        for (int mt = 0; mt < 4; ++mt)
          acc[mt] = __builtin_amdgcn_mfma_f32_16x16x32_f16(whh0[mt][kf], bf[kf],
                                                           acc[mt], 0, 0, 0);
      // ih from LDS (reuse bf regs)
#pragma unroll
      for (int kf = 0; kf < 4; ++kf)
        bf[kf] = *(const half8*)(sX + OFF(lb, kf * 32 + k0b));
#pragma unroll
      for (int kf = 0; kf < 4; ++kf)
#pragma unroll
        for (int mt = 0; mt < 4; ++mt) {
          half8 a = *(const half8*)(wi0base + (mt * 4 + kf) * 1024);
          acc[mt] = __builtin_amdgcn_mfma_f32_16x16x32_f16(a, bf[kf], acc[mt], 0, 0, 0);
        }
    }
    // ACT0
    {
      _Float16 h4[4];
#pragma unroll
      for (int mt = 0; mt < 4; ++mt) {
        float si = sigm(acc[mt][0]);
        float sf = sigm(acc[mt][1]);
        float tg = tanh_f(acc[mt][2]);
        float so = sigm(acc[mt][3]);
        float cn = sf * c0[mt] + si * tg;
        float hn = so * tanh_f(cn);
        c0[mt] = mk ? cn : c0[mt];
        h4[mt] = (_Float16)hn;
      }
      hp0v = mk ? *(half4v*)h4 : hp0v;
      *(half4v*)(sm + H0O + p * 4096 + OFF(lb, u0)) = hp0v;
    }
    BARRIER();  // h0[p] published; vmcnt stays counted

    // stage x(t+1) into XT[p^1]
    if (doX) {
      half4v hx;
      hx[0] = (_Float16)xpre[0]; hx[1] = (_Float16)xpre[1];
      hx[2] = (_Float16)xpre[2]; hx[3] = (_Float16)xpre[3];
      *(half4v*)(sm + XTO + (p ^ 1) * 4096 + OFF(xb, xk4)) = hx;
    }

    // ================= layer 1 =================
    {
      const char* sX = sm + H0O + p * 4096;  // fresh h0(t)
      const char* sH = sm + H1O + p * 4096;  // h1(t-1)
      half8 bf[4];
#pragma unroll
      for (int mt = 0; mt < 4; ++mt)
        acc[mt] = *(const f32x4*)(biasS + 512 + (u0 + mt) * 4);
#pragma unroll
      for (int kf = 0; kf < 4; ++kf)
        bf[kf] = *(const half8*)(sH + OFF(lb, kf * 32 + k0b));
#pragma unroll
      for (int kf = 0; kf < 4; ++kf)
#pragma unroll
        for (int mt = 0; mt < 4; ++mt)
          acc[mt] = __builtin_amdgcn_mfma_f32_16x16x32_f16(whh1[mt][kf], bf[kf],
                                                           acc[mt], 0, 0, 0);
#pragma unroll
      for (int kf = 0; kf < 4; ++kf)
        bf[kf] = *(const half8*)(sX + OFF(lb, kf * 32 + k0b));
#pragma unroll
      for (int kf = 0; kf < 4; ++kf)
#pragma unroll
        for (int mt = 0; mt < 4; ++mt)
          acc[mt] = __builtin_amdgcn_mfma_f32_16x16x32_f16(wi1[mt][kf], bf[kf],
                                                           acc[mt], 0, 0, 0);
    }
    // ACT1 + output
    {
      _Float16 h4[4];
      f32x4 vo;
#pragma unroll
      for (int mt = 0; mt < 4; ++mt) {
        float si = sigm(acc[mt][0]);
        float sf = sigm(acc[mt][1]);
        float tg = tanh_f(acc[mt][2]);
        float so = sigm(acc[mt][3]);
        float cn = sf * c1[mt] + si * tg;
        float hn = so * tanh_f(cn);
        c1[mt] = mk ? cn : c1[mt];
        h4[mt] = (_Float16)hn;
        vo[mt] = mk ? hn : 0.0f;
      }
      hp1v = mk ? *(half4v*)h4 : hp1v;
      *(half4v*)(sm + H1O + (p ^ 1) * 4096 + OFF(lb, u0)) = hp1v;
      *(f32x4*)optr = vo;
      optr += 128;
      if (t == 199) optr = out + obase_ar;
    }
    BARRIER();  // h1[p^1], XT[p^1] published
  }
}

extern "C" void kernel_launch(void* const* d_in, const int* in_sizes, int n_in,
                              void* d_out, int out_size, void* d_ws, size_t ws_size,
                              hipStream_t stream) {
  (void)in_sizes; (void)n_in; (void)out_size;
  const float* x = (const float*)d_in[0];
  const int* len_in = (const int*)d_in[1];
  const int* len_ar = (const int*)d_in[2];
  // d_in[3] = mask_aureg unused (monotone mask recomputed from lengths)
  const float* W_ih = (const float*)d_in[4];
  const float* W_hh = (const float*)d_in[5];
  const float* b_ih = (const float*)d_in[6];
  const float* b_hh = (const float*)d_in[7];
  float* out = (float*)d_out;
  char* ws = (char*)d_ws;

  if (ws_size >= (size_t)393216) {
    pack_kernel<<<dim3(96), dim3(256), 0, stream>>>(W_ih, W_hh, ws);
    lstm_kernel<1><<<dim3(32), dim3(512), 0, stream>>>(x, len_in, len_ar, W_ih,
                                                       W_hh, b_ih, b_hh, ws, out);
  } else {
    lstm_kernel<0><<<dim3(32), dim3(512), 0, stream>>>(x, len_in, len_ar, W_ih,
                                                       W_hh, b_ih, b_hh, ws, out);
  }
}